// Round 8
// baseline (1181.282 us; speedup 1.0000x reference)
//
#include <hip/hip_runtime.h>
#include <hip/hip_bf16.h>
#include <cstdint>
#include <cstddef>

// Problem constants (reference: N=8192, C=512, H=8)
#define NN 8192
#define CC 512
#define HH 8
#define CAP 256   // candidate slots/row; all-blind worst case ~96/row -> 16-sigma margin

typedef __attribute__((ext_vector_type(8))) short short8;   // 8 bf16 = 4 VGPRs
typedef __attribute__((ext_vector_type(4))) float f32x4;

enum { EPI_XK = 0, EPI_SIM = 1 };

__device__ __forceinline__ void gload_lds16(const void* g, void* l) {
  __builtin_amdgcn_global_load_lds(
      (const __attribute__((address_space(1))) void*)g,
      (__attribute__((address_space(3))) void*)l, 16, 0, 0);
}

__device__ __forceinline__ f32x4 mfma16(short8 a, short8 b, f32x4 c) {
  return __builtin_amdgcn_mfma_f32_16x16x32_bf16(a, b, c, 0, 0, 0);
}

__device__ __forceinline__ float b2f(unsigned u) {  // low 16 bits = bf16
  union { unsigned i; float f; } x; x.i = u << 16; return x.f;
}

__device__ __forceinline__ void unpack8(uint4 v, float* f) {
  f[0] = b2f(v.x & 0xffffu); f[1] = b2f(v.x >> 16);
  f[2] = b2f(v.y & 0xffffu); f[3] = b2f(v.y >> 16);
  f[4] = b2f(v.z & 0xffffu); f[5] = b2f(v.z >> 16);
  f[6] = b2f(v.w & 0xffffu); f[7] = b2f(v.w >> 16);
}

// monotone float<->uint encoding for atomicMax on signed floats
__device__ __forceinline__ unsigned fenc(float f) {
  unsigned u = __float_as_uint(f);
  return u ^ ((u >> 31) ? 0xFFFFFFFFu : 0x80000000u);
}
__device__ __forceinline__ float fdec(unsigned e) {
  e ^= ((e >> 31) ? 0x80000000u : 0xFFFFFFFFu);
  return __uint_as_float(e);
}

// ---------------------------------------------------------------------------
// Split-precision projection GEMM: [Q|K] = x @ [W_theta|W_phi] via
// ah*bh + ah*bl + al*bh (Markidis). Output split into bf16 hi+lo pairs
// (= fp32 to 2^-17) for later exact recompute. 128x128 tile, 48 MFMA/barrier.
// ---------------------------------------------------------------------------
__global__ __launch_bounds__(256, 2) void gemm_qk(
    const __hip_bfloat16* __restrict__ ah, const __hip_bfloat16* __restrict__ al, int lda,
    const __hip_bfloat16* __restrict__ bh, const __hip_bfloat16* __restrict__ bl, int ldb,
    int K,
    __hip_bfloat16* __restrict__ outHi, __hip_bfloat16* __restrict__ outLo, int ldc,
    const float* __restrict__ biasCol)
{
  __shared__ __align__(16) char lds[32768];  // Ah | Al | Bh | Bl, 8KB each
  const int tid  = threadIdx.x;
  const int lane = tid & 63;
  const int wave = tid >> 6;
  const int bm = blockIdx.y, bn = blockIdx.x;
  const int wr = wave >> 1, wc = wave & 1;
  const int fr = lane & 15, fq = lane >> 4;

  f32x4 acc[4][4] = {};

  for (int kt = 0; kt < K; kt += 32) {
    __syncthreads();
#pragma unroll
    for (int tile = 0; tile < 4; ++tile) {
      const __hip_bfloat16* tp = (tile == 0) ? ah : (tile == 1) ? al
                               : (tile == 2) ? bh : bl;
      const int ld = (tile < 2) ? lda : ldb;
      const int tb = ((tile < 2) ? bm : bn) * 128;
#pragma unroll
      for (int half = 0; half < 2; ++half) {
        int sub = half * 256 + tid;
        int row = sub >> 2, ch = sub & 3;
        gload_lds16(tp + (size_t)(tb + row) * ld + kt + ch * 8,
                    lds + tile * 8192 + sub * 16);
      }
    }
    __syncthreads();

    short8 fah[4], fal[4], fbh[4], fbl[4];
#pragma unroll
    for (int i = 0; i < 4; ++i) {
      const int ra = (wr * 64 + i * 16 + fr) * 64 + fq * 16;
      const int rb = (wc * 64 + i * 16 + fr) * 64 + fq * 16;
      fah[i] = *(const short8*)(lds +         ra);
      fal[i] = *(const short8*)(lds +  8192 + ra);
      fbh[i] = *(const short8*)(lds + 16384 + rb);
      fbl[i] = *(const short8*)(lds + 24576 + rb);
    }
#pragma unroll
    for (int i = 0; i < 4; ++i)
#pragma unroll
      for (int j = 0; j < 4; ++j) {
        acc[i][j] = mfma16(fah[i], fbh[j], acc[i][j]);
        acc[i][j] = mfma16(fah[i], fbl[j], acc[i][j]);
        acc[i][j] = mfma16(fal[i], fbh[j], acc[i][j]);
      }
  }

  // C/D layout: col = lane&15, row = (lane>>4)*4 + t  [m89]
#pragma unroll
  for (int i = 0; i < 4; ++i)
#pragma unroll
    for (int j = 0; j < 4; ++j) {
      const int rbase = bm * 128 + wr * 64 + i * 16 + fq * 4;
      const int col   = bn * 128 + wc * 64 + j * 16 + fr;
#pragma unroll
      for (int t = 0; t < 4; ++t) {
        float v = acc[i][j][t] + biasCol[col];
        __hip_bfloat16 h = __float2bfloat16(v);
        outHi[(size_t)(rbase + t) * ldc + col] = h;
        outLo[(size_t)(rbase + t) * ldc + col] = __float2bfloat16(v - __bfloat162float(h));
      }
    }
}

// ---------------------------------------------------------------------------
// Plain GEMM C = A*B^T, BK=32 (proven m97 structure; round-7's BK=64 regressed
// both variants 120->165us). EPI_XK: bf16 store + col bias.
// EPI_SIM: no sim store. Per-(row) wave-max -> fire-and-forget atomicMax
// (round-7 lesson: READING the atomic return made a serial 16x round-trip
// chain, +45us). Threshold = max(wave_mx, plain-loaded rowMax) - 10.5;
// loaded value is a monotone lower bound -> superset-safe; argmax always
// self-pushes since s = mx >= T.
// ---------------------------------------------------------------------------
template <int EPI>
__global__ __launch_bounds__(256, 2) void gemm_bt(
    const __hip_bfloat16* __restrict__ A, int lda,
    const __hip_bfloat16* __restrict__ B, int ldb,
    int K,
    __hip_bfloat16* __restrict__ outB, int ldc,
    const float* __restrict__ biasCol,
    unsigned* __restrict__ rowMaxEnc,
    int* __restrict__ candM, float* __restrict__ candS,
    int* __restrict__ cnt)
{
  __shared__ __align__(16) char lds[16384];  // A 8KB | B 8KB
  const int tid  = threadIdx.x;
  const int lane = tid & 63;
  const int wave = tid >> 6;
  const int bm = blockIdx.y, bn = blockIdx.x;
  const int wr = wave >> 1, wc = wave & 1;
  const int fr = lane & 15, fq = lane >> 4;

  f32x4 acc[4][4] = {};

  for (int kt = 0; kt < K; kt += 32) {
    __syncthreads();
#pragma unroll
    for (int half = 0; half < 2; ++half) {
      int sub = half * 256 + tid;
      int row = sub >> 2, ch = sub & 3;
      gload_lds16(A + (size_t)(bm * 128 + row) * lda + kt + ch * 8, lds +        sub * 16);
      gload_lds16(B + (size_t)(bn * 128 + row) * ldb + kt + ch * 8, lds + 8192 + sub * 16);
    }
    __syncthreads();

    short8 af[4], bf[4];
#pragma unroll
    for (int i = 0; i < 4; ++i) {
      af[i] = *(const short8*)(lds +        (wr * 64 + i * 16 + fr) * 64 + fq * 16);
      bf[i] = *(const short8*)(lds + 8192 + (wc * 64 + i * 16 + fr) * 64 + fq * 16);
    }
#pragma unroll
    for (int i = 0; i < 4; ++i)
#pragma unroll
      for (int j = 0; j < 4; ++j)
        acc[i][j] = mfma16(af[i], bf[j], acc[i][j]);
  }

  if constexpr (EPI == EPI_XK) {
#pragma unroll
    for (int i = 0; i < 4; ++i)
#pragma unroll
      for (int j = 0; j < 4; ++j) {
        const int rbase = bm * 128 + wr * 64 + i * 16 + fq * 4;
        const int col   = bn * 128 + wc * 64 + j * 16 + fr;
#pragma unroll
        for (int t = 0; t < 4; ++t)
          outB[(size_t)(rbase + t) * ldc + col] =
              __float2bfloat16(acc[i][j][t] + biasCol[col]);
      }
  } else {  // EPI_SIM: fused candidate push, sim never materialized
#pragma unroll
    for (int i = 0; i < 4; ++i)
#pragma unroll
      for (int t = 0; t < 4; ++t) {
        const int row = bm * 128 + wr * 64 + i * 16 + fq * 4 + t;
        float mx = acc[i][0][t];
#pragma unroll
        for (int j = 1; j < 4; ++j) mx = fmaxf(mx, acc[i][j][t]);
        mx = fmaxf(mx, __shfl_xor(mx, 1));
        mx = fmaxf(mx, __shfl_xor(mx, 2));
        mx = fmaxf(mx, __shfl_xor(mx, 4));
        mx = fmaxf(mx, __shfl_xor(mx, 8));
        const unsigned lv = rowMaxEnc[row];        // plain load: lower bound
        if (fr == 0) atomicMax(rowMaxEnc + row, fenc(mx));  // no return -> no wait
        const float live = lv ? fmaxf(mx, fdec(lv)) : mx;
        const float T = live - 10.5f;   // 10 window + 0.5 bf16-input acc error
#pragma unroll
        for (int j = 0; j < 4; ++j) {
          const float s = acc[i][j][t];
          if (s > T) {
            int slot = atomicAdd(cnt + row, 1);
            if (slot < CAP) {
              candM[(size_t)row * CAP + slot] = bn * 128 + wc * 64 + j * 16 + fr;
              candS[(size_t)row * CAP + slot] = s;
            }
          }
        }
      }
  }
}

// ---------------------------------------------------------------------------
// Fused select+gather, one WAVE per row, barrier-free (round-6 lesson).
// 1) load candidates (<=256 via 4 lane-slots), M1 = max s (true row max:
//    the argmax is always pushed).
// 2) keep s > M1-10.5; exact fp32 recompute from QK hi/lo (wave-parallel
//    dot, ~2-4 kept/row); store per-kept (s_e, m) at lane nk.
// 3) softmax weights off exact max; gather XK rows (8x1KB coalesced/row);
//    in-lane head reduce + relu; write 2x float4.
// ---------------------------------------------------------------------------
__global__ __launch_bounds__(256) void select_gather(
    const int* __restrict__ candM, const float* __restrict__ candS,
    const int* __restrict__ cnt,
    const __hip_bfloat16* __restrict__ QKhi, const __hip_bfloat16* __restrict__ QKlo,
    const __hip_bfloat16* __restrict__ XK,
    float* __restrict__ out)
{
  const int lane = threadIdx.x & 63;
  const int n = blockIdx.x * 4 + (threadIdx.x >> 6);
  const int k = min(cnt[n], CAP);

  float ss[4];
  int   mm[4];
#pragma unroll
  for (int slot = 0; slot < 4; ++slot) {
    const int idx = slot * 64 + lane;
    ss[slot] = -1e30f; mm[slot] = 0;
    if (idx < k) {
      ss[slot] = candS[(size_t)n * CAP + idx];
      mm[slot] = candM[(size_t)n * CAP + idx];
    }
  }

  float M1 = fmaxf(fmaxf(ss[0], ss[1]), fmaxf(ss[2], ss[3]));
#pragma unroll
  for (int off = 32; off; off >>= 1) M1 = fmaxf(M1, __shfl_xor(M1, off));
  const float cut = M1 - 10.5f;

  // hoist q row (hi+lo reconstruct, 8 dims/lane)
  float qf[8];
  {
    uint4 qh4 = ((const uint4*)(QKhi + (size_t)n * 1024))[lane];
    uint4 ql4 = ((const uint4*)(QKlo + (size_t)n * 1024))[lane];
    float a[8], b[8];
    unpack8(qh4, a); unpack8(ql4, b);
#pragma unroll
    for (int e = 0; e < 8; ++e) qf[e] = a[e] + b[e];
  }

  // filter + exact recompute; kept candidate i lives in lane i's (se,mm) regs
  int nk = 0;
  float se_mine = -1e30f;
  int   mm_mine = 0;
#pragma unroll
  for (int slot = 0; slot < 4; ++slot) {
    if (slot * 64 < k) {
      const int lim = min(64, k - slot * 64);
      for (int i = 0; i < lim; ++i) {
        const float si = __shfl(ss[slot], i);
        if (si > cut && nk < 64) {
          const int mi = __shfl(mm[slot], i);
          uint4 kh4 = ((const uint4*)(QKhi + (size_t)mi * 1024 + 512))[lane];
          uint4 kl4 = ((const uint4*)(QKlo + (size_t)mi * 1024 + 512))[lane];
          float a[8], b[8];
          unpack8(kh4, a); unpack8(kl4, b);
          float p = 0.f;
#pragma unroll
          for (int e = 0; e < 8; ++e) p += qf[e] * (a[e] + b[e]);
#pragma unroll
          for (int off = 32; off; off >>= 1) p += __shfl_xor(p, off);
          if (lane == nk) { se_mine = p; mm_mine = mi; }
          ++nk;
        }
      }
    }
  }

  // exact max + normalizer
  float Me = (lane < nk) ? se_mine : -1e30f;
#pragma unroll
  for (int off = 32; off; off >>= 1) Me = fmaxf(Me, __shfl_xor(Me, off));
  float wv = __expf(se_mine - Me);           // valid only for lane < nk
  float Lr = (lane < nk) ? wv : 0.f;
#pragma unroll
  for (int off = 32; off; off >>= 1) Lr += __shfl_xor(Lr, off);

  // gather
  float acc[8][8] = {};   // [head][e]
  for (int i = 0; i < nk; ++i) {
    const float w  = __shfl(wv, i);
    const int   mi = __shfl(mm_mine, i);
    const uint4* row = (const uint4*)(XK + (size_t)mi * (HH * CC));
#pragma unroll
    for (int h = 0; h < 8; ++h) {
      float f[8];
      unpack8(row[h * 64 + lane], f);
#pragma unroll
      for (int e = 0; e < 8; ++e) acc[h][e] += w * f[e];
    }
  }
  const float inv = 0.125f / Lr;
  float4 o0, o1;
  float* o0p = &o0.x; float* o1p = &o1.x;
#pragma unroll
  for (int e = 0; e < 4; ++e) {
    float t0 = 0.f, t1 = 0.f;
#pragma unroll
    for (int h = 0; h < 8; ++h) {
      t0 += fmaxf(acc[h][e],     0.f);
      t1 += fmaxf(acc[h][e + 4], 0.f);
    }
    o0p[e] = t0 * inv;
    o1p[e] = t1 * inv;
  }
  float4* orow = (float4*)(out + (size_t)n * CC + 8 * lane);
  orow[0] = o0;
  orow[1] = o1;
}

// ------------------------- prep kernels ------------------------------------
__global__ void split_kernel(const float* __restrict__ x,
                             __hip_bfloat16* __restrict__ hi,
                             __hip_bfloat16* __restrict__ lo, int n) {
  int i = blockIdx.x * 256 + threadIdx.x;
  if (i < n) {
    float v = x[i];
    __hip_bfloat16 h = __float2bfloat16(v);
    hi[i] = h;
    lo[i] = __float2bfloat16(v - __bfloat162float(h));
  }
}

__global__ void build_wt(const float* __restrict__ Wth, const float* __restrict__ Wph,
                         __hip_bfloat16* __restrict__ wthi, __hip_bfloat16* __restrict__ wtlo) {
  int idx = blockIdx.x * 256 + threadIdx.x;
  int j = idx >> 9, c = idx & 511;
  const float* W = (j < 512) ? Wth : Wph;
  float v = W[(size_t)c * 512 + (j & 511)];
  __hip_bfloat16 h = __float2bfloat16(v);
  wthi[idx] = h;
  wtlo[idx] = __float2bfloat16(v - __bfloat162float(h));
}

__global__ void build_wkt(const float* __restrict__ Wk, __hip_bfloat16* __restrict__ wkt) {
  int idx = blockIdx.x * 256 + threadIdx.x;
  int j = idx >> 9, c = idx & 511;
  float v = Wk[(size_t)(j >> 9) * 262144 + (size_t)c * 512 + (j & 511)];
  wkt[idx] = __float2bfloat16(v);
}

__global__ void build_biasqk(const float* __restrict__ bt, const float* __restrict__ bp,
                             float* __restrict__ bias) {
  int i = blockIdx.x * 256 + threadIdx.x;
  bias[i] = (i < 512) ? bt[i] : bp[i - 512];
}

extern "C" void kernel_launch(void* const* d_in, const int* in_sizes, int n_in,
                              void* d_out, int out_size, void* d_ws, size_t ws_size,
                              hipStream_t stream) {
  const float* x  = (const float*)d_in[0];
  const float* Wt = (const float*)d_in[1];
  const float* bt = (const float*)d_in[2];
  const float* Wp = (const float*)d_in[3];
  const float* bp = (const float*)d_in[4];
  const float* Wk = (const float*)d_in[5];
  const float* bk = (const float*)d_in[6];
  float* out = (float*)d_out;

  // ---- workspace layout, peak ~136.1 MiB ----
  const size_t MB = 1024 * 1024;
  char* w = (char*)d_ws;
  __hip_bfloat16* xhi  = (__hip_bfloat16*)(w + 0 * MB);    // 8 MiB
  __hip_bfloat16* xlo  = (__hip_bfloat16*)(w + 8 * MB);    // 8 MiB
  __hip_bfloat16* WkT  = (__hip_bfloat16*)(w + 16 * MB);   // 4 MiB
  __hip_bfloat16* WThi = (__hip_bfloat16*)(w + 20 * MB);   // 1 MiB
  __hip_bfloat16* WTlo = (__hip_bfloat16*)(w + 21 * MB);   // 1 MiB
  float*          biasqk = (float*)(w + 22 * MB);          // 4 KiB
  __hip_bfloat16* XK   = (__hip_bfloat16*)(w + 24 * MB);   // 64 MiB
  __hip_bfloat16* QKhi = (__hip_bfloat16*)(w + 88 * MB);   // 16 MiB
  __hip_bfloat16* QKlo = (__hip_bfloat16*)(w + 104 * MB);  // 16 MiB
  int*            candM = (int*)(w + 120 * MB);            // 8 MiB
  float*          candS = (float*)(w + 128 * MB);          // 8 MiB
  unsigned* rowMax = (unsigned*)(w + 136 * MB);            // 32 KiB
  int*      cnt    = (int*)(w + 136 * MB + 32 * 1024);     // 32 KiB

  // 1. prep
  split_kernel<<<(NN * CC + 255) / 256, 256, 0, stream>>>(x, xhi, xlo, NN * CC);
  build_wt<<<(1024 * CC) / 256, 256, 0, stream>>>(Wt, Wp, WThi, WTlo);
  build_wkt<<<(HH * CC * CC) / 256, 256, 0, stream>>>(Wk, WkT);
  build_biasqk<<<4, 256, 0, stream>>>(bt, bp, biasqk);
  hipMemsetAsync(rowMax, 0, NN * sizeof(unsigned), stream);
  hipMemsetAsync(cnt, 0, NN * sizeof(int), stream);

  // 2. [Q|K] projections, split precision, hi+lo outputs (8192 x 1024)
  gemm_qk<<<dim3(1024 / 128, NN / 128), 256, 0, stream>>>(
      xhi, xlo, CC, WThi, WTlo, CC, CC, QKhi, QKlo, 1024, biasqk);

  // 3. XK[m][j] = (x @ W_k)[m][h*512+d] + b_k, row-major for contiguous gathers
  gemm_bt<EPI_XK><<<dim3((HH * CC) / 128, NN / 128), 256, 0, stream>>>(
      xhi, CC, WkT, CC, CC, XK, HH * CC, bk, nullptr, nullptr, nullptr, nullptr);

  // 4. sim = Q @ K^T fused with candidate selection (sim never written)
  gemm_bt<EPI_SIM><<<dim3(NN / 128, NN / 128), 256, 0, stream>>>(
      QKhi, 1024, QKhi + 512, 1024, CC, nullptr, 0, nullptr,
      rowMax, candM, candS, cnt);

  // 5. fused select + exact-weight + gather (one wave per row)
  select_gather<<<NN / 4, 256, 0, stream>>>(candM, candS, cnt,
                                            QKhi, QKlo, XK, out);
}

// Round 9
// 386.155 us; speedup vs baseline: 3.0591x; 3.0591x over previous
//
#include <hip/hip_runtime.h>
#include <hip/hip_bf16.h>
#include <cstdint>
#include <cstddef>

// Problem constants (reference: N=8192, C=512, H=8)
#define NN 8192
#define CC 512
#define HH 8
#define CAP 64    // max selected entries per row (measured E[k]~2.2 @ T1=M-10)

typedef __attribute__((ext_vector_type(8))) short short8;   // 8 bf16 = 4 VGPRs
typedef __attribute__((ext_vector_type(4))) float f32x4;

__device__ __forceinline__ void gload_lds16(const void* g, void* l) {
  __builtin_amdgcn_global_load_lds(
      (const __attribute__((address_space(1))) void*)g,
      (__attribute__((address_space(3))) void*)l, 16, 0, 0);
}

__device__ __forceinline__ f32x4 mfma16(short8 a, short8 b, f32x4 c) {
  return __builtin_amdgcn_mfma_f32_16x16x32_bf16(a, b, c, 0, 0, 0);
}

__device__ __forceinline__ float b2f(unsigned u) {  // low 16 bits = bf16
  union { unsigned i; float f; } x; x.i = u << 16; return x.f;
}

// monotone float<->uint encoding for atomicMax on signed floats
__device__ __forceinline__ unsigned fenc(float f) {
  unsigned u = __float_as_uint(f);
  return u ^ ((u >> 31) ? 0xFFFFFFFFu : 0x80000000u);
}
__device__ __forceinline__ float fdec(unsigned e) {
  e ^= ((e >> 31) ? 0x80000000u : 0xFFFFFFFFu);
  return __uint_as_float(e);
}

// ---------------------------------------------------------------------------
// Split-precision projection GEMM: [Q|K] = x @ [W_theta|W_phi] via
// ah*bh + ah*bl + al*bh (Markidis). Output split into bf16 hi+lo pairs
// (= fp32 to 2^-17) for later exact recompute. 128x128 tile, 48 MFMA/barrier.
// ---------------------------------------------------------------------------
__global__ __launch_bounds__(256, 2) void gemm_qk(
    const __hip_bfloat16* __restrict__ ah, const __hip_bfloat16* __restrict__ al, int lda,
    const __hip_bfloat16* __restrict__ bh, const __hip_bfloat16* __restrict__ bl, int ldb,
    int K,
    __hip_bfloat16* __restrict__ outHi, __hip_bfloat16* __restrict__ outLo, int ldc,
    const float* __restrict__ biasCol)
{
  __shared__ __align__(16) char lds[32768];  // Ah | Al | Bh | Bl, 8KB each
  const int tid  = threadIdx.x;
  const int lane = tid & 63;
  const int wave = tid >> 6;
  const int bm = blockIdx.y, bn = blockIdx.x;
  const int wr = wave >> 1, wc = wave & 1;
  const int fr = lane & 15, fq = lane >> 4;

  f32x4 acc[4][4] = {};

  for (int kt = 0; kt < K; kt += 32) {
    __syncthreads();
#pragma unroll
    for (int tile = 0; tile < 4; ++tile) {
      const __hip_bfloat16* tp = (tile == 0) ? ah : (tile == 1) ? al
                               : (tile == 2) ? bh : bl;
      const int ld = (tile < 2) ? lda : ldb;
      const int tb = ((tile < 2) ? bm : bn) * 128;
#pragma unroll
      for (int half = 0; half < 2; ++half) {
        int sub = half * 256 + tid;
        int row = sub >> 2, ch = sub & 3;
        gload_lds16(tp + (size_t)(tb + row) * ld + kt + ch * 8,
                    lds + tile * 8192 + sub * 16);
      }
    }
    __syncthreads();

    short8 fah[4], fal[4], fbh[4], fbl[4];
#pragma unroll
    for (int i = 0; i < 4; ++i) {
      const int ra = (wr * 64 + i * 16 + fr) * 64 + fq * 16;
      const int rb = (wc * 64 + i * 16 + fr) * 64 + fq * 16;
      fah[i] = *(const short8*)(lds +         ra);
      fal[i] = *(const short8*)(lds +  8192 + ra);
      fbh[i] = *(const short8*)(lds + 16384 + rb);
      fbl[i] = *(const short8*)(lds + 24576 + rb);
    }
#pragma unroll
    for (int i = 0; i < 4; ++i)
#pragma unroll
      for (int j = 0; j < 4; ++j) {
        acc[i][j] = mfma16(fah[i], fbh[j], acc[i][j]);
        acc[i][j] = mfma16(fah[i], fbl[j], acc[i][j]);
        acc[i][j] = mfma16(fal[i], fbh[j], acc[i][j]);
      }
  }

  // C/D layout: col = lane&15, row = (lane>>4)*4 + t  [m89]
#pragma unroll
  for (int i = 0; i < 4; ++i)
#pragma unroll
    for (int j = 0; j < 4; ++j) {
      const int rbase = bm * 128 + wr * 64 + i * 16 + fq * 4;
      const int col   = bn * 128 + wc * 64 + j * 16 + fr;
#pragma unroll
      for (int t = 0; t < 4; ++t) {
        float v = acc[i][j][t] + biasCol[col];
        __hip_bfloat16 h = __float2bfloat16(v);
        outHi[(size_t)(rbase + t) * ldc + col] = h;
        outLo[(size_t)(rbase + t) * ldc + col] = __float2bfloat16(v - __bfloat162float(h));
      }
    }
}

// ---------------------------------------------------------------------------
// SIM GEMM: sim = Q @ K^T, BK=32 (proven R6 structure — R7's BK=64 and R8's
// fused-select both regressed; two-pass with materialized sim is the verified
// optimum). bf16 store + per-row fire-and-forget atomicMax of stored value.
// ---------------------------------------------------------------------------
__global__ __launch_bounds__(256, 2) void gemm_sim(
    const __hip_bfloat16* __restrict__ A, int lda,
    const __hip_bfloat16* __restrict__ B, int ldb,
    int K,
    __hip_bfloat16* __restrict__ outB, int ldc,
    unsigned* __restrict__ rowMaxEnc)
{
  __shared__ __align__(16) char lds[16384];  // A 8KB | B 8KB
  const int tid  = threadIdx.x;
  const int lane = tid & 63;
  const int wave = tid >> 6;
  const int bm = blockIdx.y, bn = blockIdx.x;
  const int wr = wave >> 1, wc = wave & 1;
  const int fr = lane & 15, fq = lane >> 4;

  f32x4 acc[4][4] = {};

  for (int kt = 0; kt < K; kt += 32) {
    __syncthreads();
#pragma unroll
    for (int half = 0; half < 2; ++half) {
      int sub = half * 256 + tid;
      int row = sub >> 2, ch = sub & 3;
      gload_lds16(A + (size_t)(bm * 128 + row) * lda + kt + ch * 8, lds +        sub * 16);
      gload_lds16(B + (size_t)(bn * 128 + row) * ldb + kt + ch * 8, lds + 8192 + sub * 16);
    }
    __syncthreads();

    short8 af[4], bf[4];
#pragma unroll
    for (int i = 0; i < 4; ++i) {
      af[i] = *(const short8*)(lds +        (wr * 64 + i * 16 + fr) * 64 + fq * 16);
      bf[i] = *(const short8*)(lds + 8192 + (wc * 64 + i * 16 + fr) * 64 + fq * 16);
    }
#pragma unroll
    for (int i = 0; i < 4; ++i)
#pragma unroll
      for (int j = 0; j < 4; ++j)
        acc[i][j] = mfma16(af[i], bf[j], acc[i][j]);
  }

#pragma unroll
  for (int i = 0; i < 4; ++i)
#pragma unroll
    for (int t = 0; t < 4; ++t) {
      const int row = bm * 128 + wr * 64 + i * 16 + fq * 4 + t;
      float mx = -1e30f;
#pragma unroll
      for (int j = 0; j < 4; ++j) {
        const int col = bn * 128 + wc * 64 + j * 16 + fr;
        __hip_bfloat16 h = __float2bfloat16(acc[i][j][t]);
        outB[(size_t)row * ldc + col] = h;
        mx = fmaxf(mx, __bfloat162float(h));
      }
      mx = fmaxf(mx, __shfl_xor(mx, 1));
      mx = fmaxf(mx, __shfl_xor(mx, 2));
      mx = fmaxf(mx, __shfl_xor(mx, 4));
      mx = fmaxf(mx, __shfl_xor(mx, 8));
      if (fr == 0) atomicMax(rowMaxEnc + row, fenc(mx));  // no return -> no wait
    }
}

// ---------------------------------------------------------------------------
// Per-row selection, vectorized scan (uint4 = 8 bf16 = 16B/lane).
// T1 = M-10 (proven R5/R6); tail (M-30, M-10] accumulated into L.
// Exact fp32 recompute of selected logits from QK hi/lo pairs.
// ---------------------------------------------------------------------------
__global__ __launch_bounds__(256) void select_kernel(
    const __hip_bfloat16* __restrict__ sim, const unsigned* __restrict__ rowMaxEnc,
    const __hip_bfloat16* __restrict__ QKhi, const __hip_bfloat16* __restrict__ QKlo,
    int* __restrict__ selIdx, float* __restrict__ selW,
    int* __restrict__ selCnt, float* __restrict__ Lout)
{
  const int n = blockIdx.x, t = threadIdx.x;
  const float M  = fdec(rowMaxEnc[n]);
  const float T1 = M - 10.0f;   // select (weights >= e^-10)
  const float T2 = M - 30.0f;   // tail floor (dropped mass ~1e-9 rel)
  __shared__ int   s_idx[CAP];
  __shared__ int   s_cnt;
  __shared__ float s_part[4];
  if (t == 0) s_cnt = 0;
  __syncthreads();

  const uint4* srow = (const uint4*)(sim + (size_t)n * NN);  // 1024 groups of 8
  float tail = 0.f;
#pragma unroll
  for (int u = 0; u < 4; ++u) {
    const int g = t + 256 * u;
    uint4 v = srow[g];
    float f0 = b2f(v.x & 0xffffu), f1 = b2f(v.x >> 16);
    float f2 = b2f(v.y & 0xffffu), f3 = b2f(v.y >> 16);
    float f4 = b2f(v.z & 0xffffu), f5 = b2f(v.z >> 16);
    float f6 = b2f(v.w & 0xffffu), f7 = b2f(v.w >> 16);
    float mx8 = fmaxf(fmaxf(fmaxf(f0, f1), fmaxf(f2, f3)),
                      fmaxf(fmaxf(f4, f5), fmaxf(f6, f7)));
    if (mx8 > T2) {   // rare: ~2-3 groups per row
      float f[8] = {f0, f1, f2, f3, f4, f5, f6, f7};
#pragma unroll
      for (int e = 0; e < 8; ++e) {
        if (f[e] > T1) {
          int slot = atomicAdd(&s_cnt, 1);
          if (slot < CAP) s_idx[slot] = g * 8 + e;
        } else if (f[e] > T2) {
          tail += __expf(f[e] - M);
        }
      }
    }
  }
#pragma unroll
  for (int off = 32; off; off >>= 1) tail += __shfl_down(tail, off);
  if ((t & 63) == 0) s_part[t >> 6] = tail;
  __syncthreads();   // covers s_cnt, s_idx, s_part

  const int k = min(s_cnt, CAP);
  float Lacc = (t == 0) ? (s_part[0] + s_part[1] + s_part[2] + s_part[3]) : 0.f;
  const __hip_bfloat16* qh = QKhi + (size_t)n * 1024;
  const __hip_bfloat16* ql = QKlo + (size_t)n * 1024;
  for (int i = 0; i < k; ++i) {
    const int m = s_idx[i];
    const __hip_bfloat16* kh = QKhi + (size_t)m * 1024 + 512;
    const __hip_bfloat16* kl = QKlo + (size_t)m * 1024 + 512;
    float p = 0.f;
    for (int c = t; c < CC; c += 256)
      p += (__bfloat162float(qh[c]) + __bfloat162float(ql[c])) *
           (__bfloat162float(kh[c]) + __bfloat162float(kl[c]));
#pragma unroll
    for (int off = 32; off; off >>= 1) p += __shfl_down(p, off);
    __syncthreads();           // s_part reuse: prior reads complete
    if ((t & 63) == 0) s_part[t >> 6] = p;
    __syncthreads();
    if (t == 0) {
      float se = s_part[0] + s_part[1] + s_part[2] + s_part[3];
      float w  = __expf(se - M);
      selIdx[(size_t)n * CAP + i] = m;
      selW [(size_t)n * CAP + i] = w;
      Lacc += w;
    }
  }
  if (t == 0) { selCnt[n] = k; Lout[n] = Lacc; }
}

// ---------------------------------------------------------------------------
// ALGEBRAIC KEY (round 9): sum_m adj[n,m]*(x W_k + b_k) = (sum adj*x) W_k + b_k.
// zgather: z[n] = (sum_i w_i x[m_i]) / L_n  in fp32 from the ORIGINAL x,
// stored bf16. One wave per row, barrier-free (round-6 lesson). Gather rows
// are 2KB fp32 (vs 8KB XK rows before) and the XK GEMM disappears entirely.
// ---------------------------------------------------------------------------
__global__ __launch_bounds__(256) void zgather(
    const float* __restrict__ x,
    const int* __restrict__ selIdx, const float* __restrict__ selW,
    const int* __restrict__ selCnt, const float* __restrict__ L,
    __hip_bfloat16* __restrict__ z)
{
  const int lane = threadIdx.x & 63;
  const int n = blockIdx.x * 4 + (threadIdx.x >> 6);
  const int k = min(selCnt[n], CAP);
  const int   midx = (lane < k) ? selIdx[(size_t)n * CAP + lane] : 0;
  const float wval = (lane < k) ? selW [(size_t)n * CAP + lane] : 0.f;

  float acc[8] = {};   // cols 8*lane .. 8*lane+7
  for (int i = 0; i < k; ++i) {
    const int   m = __shfl(midx, i);
    const float w = __shfl(wval, i);
    const float4* row = (const float4*)(x + (size_t)m * CC + 8 * lane);
    float4 a = row[0], b = row[1];
    acc[0] += w * a.x; acc[1] += w * a.y; acc[2] += w * a.z; acc[3] += w * a.w;
    acc[4] += w * b.x; acc[5] += w * b.y; acc[6] += w * b.z; acc[7] += w * b.w;
  }
  const float inv = 1.0f / L[n];
  short8 o;
#pragma unroll
  for (int e = 0; e < 8; ++e) {
    __hip_bfloat16 h = __float2bfloat16(acc[e] * inv);
    o[e] = *(short*)&h;
  }
  *(short8*)(z + (size_t)n * CC + 8 * lane) = o;
}

// ---------------------------------------------------------------------------
// gemm_zwk: partial[n][d] = sum_{h in group} relu( (z @ WkT^T)[n][h*512+d]
//                                                  + b_k[h][d] )
// grid (4 d-tiles, 64 n-tiles, 2 head-groups); per block: 4 heads x 16
// k-steps sharing the A-tile (z) from L2; relu-accumulate in 64 fp32 regs;
// plain fp32 stores (no atomics). combine() then sums the 2 groups * 1/8.
// ---------------------------------------------------------------------------
__global__ __launch_bounds__(256, 2) void gemm_zwk(
    const __hip_bfloat16* __restrict__ z,
    const __hip_bfloat16* __restrict__ WkT,
    const float* __restrict__ bk,
    float* __restrict__ partial)   // [2][NN][CC], this block writes group hg
{
  __shared__ __align__(16) char lds[16384];  // A 8KB | B 8KB
  const int tid  = threadIdx.x;
  const int lane = tid & 63;
  const int wave = tid >> 6;
  const int bn = blockIdx.x, bm = blockIdx.y, hg = blockIdx.z;
  const int wr = wave >> 1, wc = wave & 1;
  const int fr = lane & 15, fq = lane >> 4;

  f32x4 oacc[4][4] = {};

  for (int hh = 0; hh < 4; ++hh) {
    const int head = hg * 4 + hh;
    const __hip_bfloat16* B = WkT + (size_t)(head * 512 + bn * 128) * CC;
    f32x4 acc[4][4] = {};
    for (int kt = 0; kt < CC; kt += 32) {
      __syncthreads();
#pragma unroll
      for (int half = 0; half < 2; ++half) {
        int sub = half * 256 + tid;
        int row = sub >> 2, ch = sub & 3;
        gload_lds16(z + (size_t)(bm * 128 + row) * CC + kt + ch * 8, lds +        sub * 16);
        gload_lds16(B + (size_t)row * CC + kt + ch * 8,              lds + 8192 + sub * 16);
      }
      __syncthreads();

      short8 af[4], bf[4];
#pragma unroll
      for (int i = 0; i < 4; ++i) {
        af[i] = *(const short8*)(lds +        (wr * 64 + i * 16 + fr) * 64 + fq * 16);
        bf[i] = *(const short8*)(lds + 8192 + (wc * 64 + i * 16 + fr) * 64 + fq * 16);
      }
#pragma unroll
      for (int i = 0; i < 4; ++i)
#pragma unroll
        for (int j = 0; j < 4; ++j)
          acc[i][j] = mfma16(af[i], bf[j], acc[i][j]);
    }
    // relu-accumulate this head (bias per output col)
#pragma unroll
    for (int j = 0; j < 4; ++j) {
      const int d = bn * 128 + wc * 64 + j * 16 + fr;
      const float bias = bk[head * CC + d];
#pragma unroll
      for (int i = 0; i < 4; ++i)
#pragma unroll
        for (int t = 0; t < 4; ++t)
          oacc[i][j][t] += fmaxf(acc[i][j][t] + bias, 0.f);
    }
  }

  float* dst = partial + (size_t)hg * NN * CC;
#pragma unroll
  for (int i = 0; i < 4; ++i)
#pragma unroll
    for (int j = 0; j < 4; ++j) {
      const int rbase = bm * 128 + wr * 64 + i * 16 + fq * 4;
      const int d     = bn * 128 + wc * 64 + j * 16 + fr;
#pragma unroll
      for (int t = 0; t < 4; ++t)
        dst[(size_t)(rbase + t) * CC + d] = oacc[i][j][t];
    }
}

// out = 0.125 * (p0 + p1)
__global__ void combine(const float* __restrict__ p0, const float* __restrict__ p1,
                        float* __restrict__ out) {
  int i = blockIdx.x * 256 + threadIdx.x;
  float4 a = ((const float4*)p0)[i];
  float4 b = ((const float4*)p1)[i];
  float4 o;
  o.x = 0.125f * (a.x + b.x); o.y = 0.125f * (a.y + b.y);
  o.z = 0.125f * (a.z + b.z); o.w = 0.125f * (a.w + b.w);
  ((float4*)out)[i] = o;
}

// ------------------------- prep kernels ------------------------------------
__global__ void split_kernel(const float* __restrict__ x,
                             __hip_bfloat16* __restrict__ hi,
                             __hip_bfloat16* __restrict__ lo, int n) {
  int i = blockIdx.x * 256 + threadIdx.x;
  if (i < n) {
    float v = x[i];
    __hip_bfloat16 h = __float2bfloat16(v);
    hi[i] = h;
    lo[i] = __float2bfloat16(v - __bfloat162float(h));
  }
}

__global__ void build_wt(const float* __restrict__ Wth, const float* __restrict__ Wph,
                         __hip_bfloat16* __restrict__ wthi, __hip_bfloat16* __restrict__ wtlo) {
  int idx = blockIdx.x * 256 + threadIdx.x;
  int j = idx >> 9, c = idx & 511;
  const float* W = (j < 512) ? Wth : Wph;
  float v = W[(size_t)c * 512 + (j & 511)];
  __hip_bfloat16 h = __float2bfloat16(v);
  wthi[idx] = h;
  wtlo[idx] = __float2bfloat16(v - __bfloat162float(h));
}

__global__ void build_wkt(const float* __restrict__ Wk, __hip_bfloat16* __restrict__ wkt) {
  int idx = blockIdx.x * 256 + threadIdx.x;
  int j = idx >> 9, c = idx & 511;
  float v = Wk[(size_t)(j >> 9) * 262144 + (size_t)c * 512 + (j & 511)];
  wkt[idx] = __float2bfloat16(v);
}

__global__ void build_biasqk(const float* __restrict__ bt, const float* __restrict__ bp,
                             float* __restrict__ bias) {
  int i = blockIdx.x * 256 + threadIdx.x;
  bias[i] = (i < 512) ? bt[i] : bp[i - 512];
}

extern "C" void kernel_launch(void* const* d_in, const int* in_sizes, int n_in,
                              void* d_out, int out_size, void* d_ws, size_t ws_size,
                              hipStream_t stream) {
  const float* x  = (const float*)d_in[0];
  const float* Wt = (const float*)d_in[1];
  const float* bt = (const float*)d_in[2];
  const float* Wp = (const float*)d_in[3];
  const float* bp = (const float*)d_in[4];
  const float* Wk = (const float*)d_in[5];
  const float* bk = (const float*)d_in[6];
  float* out = (float*)d_out;

  // ---- workspace layout, peak ~208.1 MiB ----
  const size_t MB = 1024 * 1024;
  char* w = (char*)d_ws;
  __hip_bfloat16* sim  = (__hip_bfloat16*)w;               // [0, 128 MiB)
  // QK-phase temps live INSIDE the sim region (dead before sim is written):
  __hip_bfloat16* xhi  = (__hip_bfloat16*)(w + 0 * MB);    // 8 MiB
  __hip_bfloat16* xlo  = (__hip_bfloat16*)(w + 8 * MB);    // 8 MiB
  __hip_bfloat16* WThi = (__hip_bfloat16*)(w + 16 * MB);   // 1 MiB
  __hip_bfloat16* WTlo = (__hip_bfloat16*)(w + 17 * MB);   // 1 MiB
  float*          biasqk = (float*)(w + 18 * MB);          // 4 KiB
  __hip_bfloat16* WkT  = (__hip_bfloat16*)(w + 128 * MB);  // 4 MiB (live till gemm_zwk!)
  __hip_bfloat16* QKhi = (__hip_bfloat16*)(w + 132 * MB);  // 16 MiB
  __hip_bfloat16* QKlo = (__hip_bfloat16*)(w + 148 * MB);  // 16 MiB
  __hip_bfloat16* z    = (__hip_bfloat16*)(w + 164 * MB);  // 8 MiB
  float*          part = (float*)(w + 172 * MB);           // 2 x 16 MiB
  int*            selIdx = (int*)(w + 204 * MB);           // 2 MiB
  float*          selW   = (float*)(w + 206 * MB);         // 2 MiB
  unsigned* rowMax = (unsigned*)(w + 208 * MB);            // 32 KiB
  int*      selCnt = (int*)(w + 208 * MB + 32 * 1024);     // 32 KiB
  float*    L      = (float*)(w + 208 * MB + 64 * 1024);   // 32 KiB

  // 1. prep
  split_kernel<<<(NN * CC + 255) / 256, 256, 0, stream>>>(x, xhi, xlo, NN * CC);
  build_wt<<<(1024 * CC) / 256, 256, 0, stream>>>(Wt, Wp, WThi, WTlo);
  build_wkt<<<(HH * CC * CC) / 256, 256, 0, stream>>>(Wk, WkT);
  build_biasqk<<<4, 256, 0, stream>>>(bt, bp, biasqk);
  hipMemsetAsync(rowMax, 0, NN * sizeof(unsigned), stream);

  // 2. [Q|K] projections, split precision, hi+lo outputs (8192 x 1024)
  gemm_qk<<<dim3(1024 / 128, NN / 128), 256, 0, stream>>>(
      xhi, xlo, CC, WThi, WTlo, CC, CC, QKhi, QKlo, 1024, biasqk);

  // 3. sim = Q @ K^T (bf16 store over the dead temps) + row maxima
  gemm_sim<<<dim3(NN / 128, NN / 128), 256, 0, stream>>>(
      QKhi, 1024, QKhi + 512, 1024, CC, sim, NN, rowMax);

  // 4. per-row top selection + exact weights + normalizer
  select_kernel<<<NN, 256, 0, stream>>>(sim, rowMax, QKhi, QKlo,
                                        selIdx, selW, selCnt, L);

  // 5. z[n] = (sum_i w_i x[m_i]) / L_n  (fp32 gather in x-space -> bf16)
  zgather<<<NN / 4, 256, 0, stream>>>(x, selIdx, selW, selCnt, L, z);

  // 6. partial[hg][n][d] = sum_{h in hg} relu(z @ W_k[h] + b_k[h])
  gemm_zwk<<<dim3(CC / 128, NN / 128, 2), 256, 0, stream>>>(z, WkT, bk, part);

  // 7. out = (partial0 + partial1) / 8
  combine<<<(NN * CC / 4) / 256, 256, 0, stream>>>(part, part + (size_t)NN * CC, out);
}